// Round 6
// baseline (147.023 us; speedup 1.0000x reference)
//
#include <hip/hip_runtime.h>
#include <math.h>

#define NO 10
#define NFEAT 68
#define MAXLIST 1024   // max incident-edge entries per atom (avg ~60)
#define MAXSLOT 128    // max distinct neighbor atoms (incl self) per atom
#define MAXN 256       // max atom count supported

// Feature f -> (orbital row oi, orbital col oj, factor)
__device__ const int g_oi[NFEAT] = {
    0,0,0,0,0,0,0,0,0,0,
    1,1,1,1,1,1,1,1,1,
    2,2,2,3,3,3,4,4,4,
    2,2,2,2,2,3,3,3,3,3,4,4,4,4,4,
    5,5,5,5,5,6,6,6,6,6,7,7,7,7,7,8,8,8,8,8,9,9,9,9,9
};
__device__ const int g_oj[NFEAT] = {
    0,1,2,3,4,5,6,7,8,9,
    1,2,3,4,5,6,7,8,9,
    2,3,4,2,3,4,2,3,4,
    5,6,7,8,9,5,6,7,8,9,5,6,7,8,9,
    5,6,7,8,9,5,6,7,8,9,5,6,7,8,9,5,6,7,8,9,5,6,7,8,9
};
__device__ const float g_fac[NFEAT] = {
    0.5f,1,1,1,1,1,1,1,1,1,
    0.5f,1,1,1,1,1,1,1,1,
    0.5f,0.5f,0.5f,0.5f,0.5f,0.5f,0.5f,0.5f,0.5f,
    1,1,1,1,1,1,1,1,1,1,1,1,1,1,1,
    0.5f,0.5f,0.5f,0.5f,0.5f,0.5f,0.5f,0.5f,0.5f,0.5f,
    0.5f,0.5f,0.5f,0.5f,0.5f,0.5f,0.5f,0.5f,0.5f,0.5f,
    0.5f,0.5f,0.5f,0.5f,0.5f
};

// Kernel A: pure streaming zero fill (fill-kernel pattern, ~6.8 TB/s proven).
__global__ void zero_kernel(float* __restrict__ out, size_t n_floats) {
    size_t n4 = n_floats >> 2;
    float4* o4 = (float4*)out;
    float4 z = make_float4(0.f, 0.f, 0.f, 0.f);
    size_t stride = (size_t)gridDim.x * blockDim.x;
    for (size_t x = (size_t)blockIdx.x * blockDim.x + threadIdx.x; x < n4; x += stride)
        o4[x] = z;
    size_t tid = (size_t)blockIdx.x * blockDim.x + threadIdx.x;
    size_t tail = n4 << 2;
    if (tid < (n_floats - tail)) out[tail + tid] = 0.f;
}

// Kernel B: owner-computes per (atom i, kpoint k). Accumulates the nonzero
// column-blocks of rows [i*NO, i*NO+NO) in a compact LDS tile, then writes
// ONLY those blocks (zeros already present from kernel A). No global atomics;
// each output float written by exactly one workgroup.
__global__ __launch_bounds__(512)
void sparse_kernel(const float* __restrict__ ef, const float* __restrict__ nf,
                   const float* __restrict__ ev, const float* __restrict__ ecs,
                   const float* __restrict__ kp, const int* __restrict__ eidx,
                   float* __restrict__ out,
                   int E, int N, int NK, size_t lim) {
    __shared__ float acc[NO * MAXSLOT * 10];   // 51.2 KB compact accumulator
    __shared__ float sins[MAXLIST];
    __shared__ int   elist[MAXLIST];           // entry = e*2 + dir
    __shared__ int   map[MAXN];                // atom j -> slot (-1 none, -2 claimed)
    __shared__ int   slotj[MAXSLOT];           // slot -> atom j
    __shared__ int   mcnt, scnt;

    const int i   = blockIdx.x;
    const int k   = blockIdx.y;
    const int tid = threadIdx.x;
    const int nthr = blockDim.x;
    const int NR  = N * NO;
    if (N > MAXN) return;

    if (tid == 0) { mcnt = 0; scnt = 1; }
    for (int x = tid; x < MAXN; x += nthr) map[x] = -1;
    __syncthreads();
    if (tid == 0) { map[i] = -2; slotj[0] = i; }   // slot 0 = self (diag block)
    __syncthreads();

    // Scan edge headers for edges incident to atom i (either endpoint).
    for (int e = tid; e < E; e += nthr) {
        int s = eidx[e], t = eidx[E + e];
        if (s == i) { int p = atomicAdd(&mcnt, 1); if (p < MAXLIST) elist[p] = e * 2; }
        if (t == i) { int p = atomicAdd(&mcnt, 1); if (p < MAXLIST) elist[p] = e * 2 + 1; }
    }
    __syncthreads();
    const int m = min(mcnt, MAXLIST);

    // Per-entry sin(2pi k.R) + claim neighbor slots.
    const float k0 = kp[k * 3 + 0], k1 = kp[k * 3 + 1], k2 = kp[k * 3 + 2];
    const float TWO_PI = 6.283185307179586f;
    for (int t = tid; t < m; t += nthr) {
        int ent = elist[t];
        int e = ent >> 1, dir = ent & 1;
        float th = TWO_PI * (k0 * ecs[e * 3 + 0] + k1 * ecs[e * 3 + 1] + k2 * ecs[e * 3 + 2]);
        sins[t] = sinf(th);
        int j = dir ? eidx[e] : eidx[E + e];     // other endpoint
        if (atomicCAS(&map[j], -1, -2) == -1) {
            int s = atomicAdd(&scnt, 1);
            if (s < MAXSLOT) slotj[s] = j;
        }
    }
    __syncthreads();
    const int ns = min(scnt, MAXSLOT);
    for (int s = tid; s < ns; s += nthr) map[slotj[s]] = s;   // final slot ids
    __syncthreads();

    const int items = m * NFEAT;
    const float4 z4 = make_float4(0.f, 0.f, 0.f, 0.f);

    for (int d = 0; d < 3; ++d) {
        // zero compact accumulator
        for (int x = tid; x < NO * MAXSLOT * 10 / 4; x += nthr)
            ((float4*)acc)[x] = z4;
        __syncthreads();

        // scatter incident-edge contributions (LDS atomics)
        for (int it = tid; it < items; it += nthr) {
            int t   = it / NFEAT;
            int f   = it - t * NFEAT;
            int ent = elist[t];
            int e   = ent >> 1;
            int dir = ent & 1;
            int row = dir ? g_oj[f] : g_oi[f];
            int col = dir ? g_oi[f] : g_oj[f];
            int j   = dir ? eidx[e] : eidx[E + e];
            int s   = map[j];
            if ((unsigned)s < MAXSLOT) {
                float val = -ev[e * 3 + d] * sins[t] * g_fac[f] * ef[e * NFEAT + f];
                atomicAdd(&acc[(row * MAXSLOT + s) * 10 + col], val);
            }
        }
        // onsite diagonal block D + D^T into slot 0
        for (int f = tid; f < NFEAT; f += nthr) {
            float v = g_fac[f] * nf[i * NFEAT + f];
            atomicAdd(&acc[(g_oi[f] * MAXSLOT + 0) * 10 + g_oj[f]], v);
            atomicAdd(&acc[(g_oj[f] * MAXSLOT + 0) * 10 + g_oi[f]], v);
        }
        __syncthreads();

        // write only the nonzero column-blocks
        size_t rowbase = ((size_t)(d * NK + k)) * NR * NR + (size_t)(i * NO) * NR;
        int total = ns * 100;                       // ns blocks x 10 rows x 10 cols
        for (int x = tid; x < total; x += nthr) {
            int s   = x / 100;
            int rem = x - s * 100;
            int r   = rem / 10;
            int c   = rem - r * 10;
            size_t idx = rowbase + (size_t)r * NR + (size_t)slotj[s] * NO + c;
            if (idx < lim) out[idx] = acc[(r * MAXSLOT + s) * 10 + c];
        }
        __syncthreads();
    }
}

extern "C" void kernel_launch(void* const* d_in, const int* in_sizes, int n_in,
                              void* d_out, int out_size, void* d_ws, size_t ws_size,
                              hipStream_t stream) {
    const float* ef  = (const float*)d_in[0];   // edge_features   [E,68]
    const float* nf  = (const float*)d_in[1];   // node_features   [N,68]
    const float* ev  = (const float*)d_in[2];   // edge_vectors    [E,3]
    const float* ecs = (const float*)d_in[3];   // edge_cell_shift [E,3]
    const float* kp  = (const float*)d_in[4];   // kpoints         [NK,3]
    const int*  eidx = (const int*)d_in[5];     // edge_index      [2,E]
    float* out = (float*)d_out;

    int E  = in_sizes[0] / NFEAT;
    int N  = in_sizes[1] / NFEAT;
    int NK = in_sizes[4] / 3;

    size_t lim = (size_t)out_size;   // out_size = 3*NK*(N*NO)^2 floats (real part)

    zero_kernel<<<2048, 256, 0, stream>>>(out, lim);

    dim3 grid(N, NK);                // (200, 4) = 800 workgroups
    sparse_kernel<<<grid, 512, 0, stream>>>(ef, nf, ev, ecs, kp, eidx, out, E, N, NK, lim);
}

// Round 7
// 95.096 us; speedup vs baseline: 1.5460x; 1.5460x over previous
//
#include <hip/hip_runtime.h>
#include <math.h>

#define NO 10
#define NFEAT 68
#define MAXLIST 1024   // max incident-edge entries per atom (avg ~60)
#define MAXNR 2048     // max N*NO supported (N=200 -> 2000)
#define HR 5           // orbital rows per workgroup (NO/2)

// Packed feature table: bits 0-3 = oi, bits 4-7 = oj, bit 8 = (fac==0.5)
__device__ const unsigned short g_pk[NFEAT] = {
    // f 0-9: oi=0, oj=0..9, fac 0.5 only at (0,0)
    0x100, 0x010, 0x020, 0x030, 0x040, 0x050, 0x060, 0x070, 0x080, 0x090,
    // f 10-18: oi=1, oj=1..9, fac 0.5 at (1,1)
    0x111, 0x021, 0x031, 0x041, 0x051, 0x061, 0x071, 0x081, 0x091,
    // f 19-27: p-p block oi=2..4, oj=2..4, all fac 0.5
    0x122, 0x132, 0x142, 0x123, 0x133, 0x143, 0x124, 0x134, 0x144,
    // f 28-42: p-d block oi=2..4, oj=5..9, fac 1
    0x052, 0x062, 0x072, 0x082, 0x092,
    0x053, 0x063, 0x073, 0x083, 0x093,
    0x054, 0x064, 0x074, 0x084, 0x094,
    // f 43-67: d-d block oi=5..9, oj=5..9, all fac 0.5
    0x155, 0x165, 0x175, 0x185, 0x195,
    0x156, 0x166, 0x176, 0x186, 0x196,
    0x157, 0x167, 0x177, 0x187, 0x197,
    0x158, 0x168, 0x178, 0x188, 0x198,
    0x159, 0x169, 0x179, 0x189, 0x199
};

// One workgroup per (atom i, kpoint k, direction d, row-half h):
// computes output rows [i*NO + h*HR, +HR) x all NR columns for direction d,
// entirely in LDS, then streams them out coalesced. 192 MB written exactly once.
__global__ __launch_bounds__(512)
void fused1d(const float* __restrict__ ef, const float* __restrict__ nf,
             const float* __restrict__ ev, const float* __restrict__ ecs,
             const float* __restrict__ kp, const int* __restrict__ eidx,
             float* __restrict__ out,
             int E, int N, int NK, size_t lim) {
    __shared__ float acc[HR * MAXNR];   // 40 KB, packed with stride NR at runtime
    __shared__ float coef[MAXLIST];     // -v_d * sin(2pi k.R) per incident entry
    __shared__ int   elist[MAXLIST];    // entry = e*2 + dir
    __shared__ int   mcnt;

    const int i   = blockIdx.x;
    const int k   = blockIdx.y;
    const int d   = blockIdx.z >> 1;
    const int h   = blockIdx.z & 1;
    const int r0  = h * HR;
    const int tid = threadIdx.x;
    const int nthr = blockDim.x;
    const int NR  = N * NO;
    if (NR > MAXNR) return;

    if (tid == 0) mcnt = 0;
    __syncthreads();

    // Phase 1: scan edge headers for incident edges; zero acc in the same phase.
    for (int e = tid; e < E; e += nthr) {
        int s = eidx[e], t = eidx[E + e];
        if (s == i) { int p = atomicAdd(&mcnt, 1); if (p < MAXLIST) elist[p] = e * 2; }
        if (t == i) { int p = atomicAdd(&mcnt, 1); if (p < MAXLIST) elist[p] = e * 2 + 1; }
    }
    {
        float4* a4 = (float4*)acc;
        int nz = (HR * NR) >> 2;
        float4 z = make_float4(0.f, 0.f, 0.f, 0.f);
        for (int x = tid; x < nz; x += nthr) a4[x] = z;
    }
    __syncthreads();
    const int m = min(mcnt, MAXLIST);

    // Phase 2: per-entry coefficient  -v_d * sin(2pi k.R)
    const float k0 = kp[k * 3 + 0], k1 = kp[k * 3 + 1], k2 = kp[k * 3 + 2];
    const float TWO_PI = 6.283185307179586f;
    for (int t = tid; t < m; t += nthr) {
        int e = elist[t] >> 1;
        float th = TWO_PI * (k0 * ecs[e * 3 + 0] + k1 * ecs[e * 3 + 1] + k2 * ecs[e * 3 + 2]);
        coef[t] = -ev[e * 3 + d] * sinf(th);
    }
    __syncthreads();

    // Phase 3: scatter edge + diagonal contributions into owned rows (LDS atomics)
    const int items = m * NFEAT;
    for (int it = tid; it < items; it += nthr) {
        int t   = it / NFEAT;
        int f   = it - t * NFEAT;
        int ent = elist[t];
        int e   = ent >> 1;
        int dir = ent & 1;
        unsigned pk = g_pk[f];
        int oi = pk & 15, oj = (pk >> 4) & 15;
        int row = dir ? oj : oi;
        int rr  = row - r0;
        if ((unsigned)rr < HR) {
            int col = dir ? oi : oj;
            int j   = dir ? eidx[e] : eidx[E + e];
            float fac = (pk & 256) ? 0.5f : 1.0f;
            float val = coef[t] * fac * ef[e * NFEAT + f];
            atomicAdd(&acc[rr * NR + j * NO + col], val);
        }
    }
    // onsite diagonal block D + D^T at (i,i)
    for (int f = tid; f < NFEAT; f += nthr) {
        unsigned pk = g_pk[f];
        int oi = pk & 15, oj = (pk >> 4) & 15;
        float v = ((pk & 256) ? 0.5f : 1.0f) * nf[i * NFEAT + f];
        int ra = oi - r0, rb = oj - r0;
        if ((unsigned)ra < HR) atomicAdd(&acc[ra * NR + i * NO + oj], v);
        if ((unsigned)rb < HR) atomicAdd(&acc[rb * NR + i * NO + oi], v);
    }
    __syncthreads();

    // Phase 4 (terminal, no trailing barrier): stream the 5 owned rows out.
    // Rows are contiguous in output: one flat 40 KB coalesced copy.
    size_t base = ((size_t)(d * NK + k)) * NR * NR + (size_t)(i * NO + r0) * NR;
    int ntot = HR * NR;
    if (((NR & 3) == 0)) {
        const float4* a4 = (const float4*)acc;
        int n4 = ntot >> 2;
        for (int x = tid; x < n4; x += nthr) {
            size_t idx = base + (size_t)x * 4;
            if (idx + 3 < lim) *(float4*)(out + idx) = a4[x];
        }
    } else {
        for (int x = tid; x < ntot; x += nthr) {
            size_t idx = base + x;
            if (idx < lim) out[idx] = acc[x];
        }
    }
}

extern "C" void kernel_launch(void* const* d_in, const int* in_sizes, int n_in,
                              void* d_out, int out_size, void* d_ws, size_t ws_size,
                              hipStream_t stream) {
    const float* ef  = (const float*)d_in[0];   // edge_features   [E,68]
    const float* nf  = (const float*)d_in[1];   // node_features   [N,68]
    const float* ev  = (const float*)d_in[2];   // edge_vectors    [E,3]
    const float* ecs = (const float*)d_in[3];   // edge_cell_shift [E,3]
    const float* kp  = (const float*)d_in[4];   // kpoints         [NK,3]
    const int*  eidx = (const int*)d_in[5];     // edge_index      [2,E]
    float* out = (float*)d_out;

    int E  = in_sizes[0] / NFEAT;
    int N  = in_sizes[1] / NFEAT;
    int NK = in_sizes[4] / 3;

    size_t lim = (size_t)out_size;   // out_size = 3*NK*(N*NO)^2 floats (real part)

    dim3 grid(N, NK, 3 * 2);         // (200, 4, 6) = 4800 workgroups
    fused1d<<<grid, 512, 0, stream>>>(ef, nf, ev, ecs, kp, eidx, out, E, N, NK, lim);
}